// Round 4
// baseline (105.010 us; speedup 1.0000x reference)
//
#include <hip/hip_runtime.h>

#define LOG2E 1.4426950408889634f
#define LN2F  0.6931471805599453f
#define RS5F  0.4472135954999579f  // 1/sqrt(5)

// single-instruction ds_swizzle (BitMode: src = ((lane & AND) | OR) ^ XOR, 32-lane groups)
template<int XOR, int OR, int AND>
__device__ __forceinline__ float swz(float v) {
    return __int_as_float(__builtin_amdgcn_ds_swizzle(
        __float_as_int(v), (XOR << 10) | (OR << 5) | AND));
}
#define EXP2(x)  __builtin_amdgcn_exp2f(x)   // raw v_exp_f32
#define LOG2_(x) __builtin_amdgcn_logf(x)    // raw v_log_f32
#define RCP_(x)  __builtin_amdgcn_rcpf(x)    // raw v_rcp_f32

// DPP cross-lane (full-rate VALU, no LDS pipe): XOR patterns within 16-lane rows.
template<int CTRL>
__device__ __forceinline__ float dppf(float v) {
    return __int_as_float(__builtin_amdgcn_update_dpp(
        0, __float_as_int(v), CTRL, 0xF, 0xF, true));
}
#define DPPX1(v)  dppf<0xB1>(v)    // quad_perm [1,0,3,2] : xor 1
#define DPPX2(v)  dppf<0x4E>(v)    // quad_perm [2,3,0,1] : xor 2
#define DPPX3(v)  dppf<0x1B>(v)    // quad_perm [3,2,1,0] : xor 3
#define DPPX8(v)  dppf<0x128>(v)   // row_ror:8           : xor 8 (within 16)
#define DPPHM(v)  dppf<0x141>(v)   // row_half_mirror     : xor 7
#define DPPRM(v)  dppf<0x140>(v)   // row_mirror          : xor 15
#define DPPX4(v)  DPPX3(DPPHM(v))  // xor 4 = xor7 then xor3
#define DPPX12(v) DPPX3(DPPRM(v))  // xor 12 = xor15 then xor3

__device__ __forceinline__ float bperm(int byte_addr, float v) {
    return __int_as_float(__builtin_amdgcn_ds_bpermute(byte_addr, __float_as_int(v)));
}

// 4 items per WAVE (16-lane item groups, 16 items per 256-block).
// Lane u = lane&15 holds state entry u (row=u>>2, col=u&3) — no mirror.
// Combo digits: c1 = u>>2 (bits 2-3), c2 = u&3 (bits 0-1); in-lane j in [0,8):
// c0A = j>>2 in {0,1}, c3A = j&3. C-combo = all-digit complement (c0C in {3,2}).
// 16 lanes x 8 j x {A,C} = 256 combos. Exactness: per-row max shifted out at
// load; NO mid-round renorms (non-updated rows have max 0, softmax is
// shift-invariant, blend inputs untouched since load); single final renorm.
// ROUND-3 PROBE: kernel body unchanged; kernel_launch enqueues 3 identical
// (idempotent) dispatches to expose T_kernel = (dur_us - baseline)/2.
__global__ __launch_bounds__(256, 4) void mfnet_layer_kernel(
    const float* __restrict__ log_qi,   // (N,4,4)
    const float* __restrict__ G,        // (N,8,4)
    const float* __restrict__ sqrt_2rho,// (N,)
    const float* __restrict__ alpha_ptr,// (1,)
    float* __restrict__ out,            // (N,4,4)
    int N)
{
    const int tid  = threadIdx.x;
    const int wv   = tid >> 6;
    const int lane = tid & 63;
    const int grp  = (lane >> 4) & 3;    // item within wave
    const int u    = lane & 15;
    const int ib   = blockIdx.x * 16 + wv * 4;

    // G staging: 4 items x 32 floats, item stride 40 (bases at banks 0/8/16/24
    // -> conflict-free 16B group-broadcast reads). Wave-local, no __syncthreads.
    __shared__ __align__(16) float sG[4][160];
    {
        size_t gidx = (size_t)ib * 32 + (size_t)(lane * 2);   // = ib*32 + 2*lane, coalesced
        size_t gmax = (size_t)N * 32 - 2;
        if (gidx > gmax) gidx = gmax;
        float2 gv = *(const float2*)(G + gidx);
        *(float2*)&sG[wv][grp * 40 + u * 2] = gv;
    }

    const int it0    = ib + grp;
    const bool valid = (it0 < N);
    const int item   = valid ? it0 : (N - 1);

    const float alpha = alpha_ptr[0];
    const float alm1  = 1.0f - alpha;

    const int col = u & 3;               // state col, also c2
    const int row = u >> 2;              // state row, also c1

    // symbols with LOG2E folded in (whole pipeline in log2 units)
    const float rv = sqrt_2rho[item] * (RS5F * LOG2E);
    const float s1 = rv * (float)(2 * row - 3);
    const float s2 = rv * (float)(2 * col - 3);

    // distributed state, log2 units; shift out each row's initial max
    float slqD = log_qi[(size_t)item * 16 + u] * LOG2E;   // addr = ib*16+lane, coalesced
    {
        float m1 = fmaxf(slqD, DPPX1(slqD));
        float m  = fmaxf(m1, DPPX2(m1));
        slqD -= m;
    }

    // softmax of all rows at once (4-lane packs) — DPP reductions
    auto softmax_all = [&](float s) {
        float e   = EXP2(s);
        float t   = e + DPPX1(e);
        float den = t + DPPX2(t);
        return e * RCP_(den);
    };
    float qD = softmax_all(slqD);

    // bpermute byte addresses (only where the source index needs shifted lane bits)
    const int gb   = (lane & 0x30) << 2;             // group-base byte address
    const int aQ1A = gb + ((4 + row) << 2);          // q_row1[c1]
    const int aQ1C = gb + ((4 + (row ^ 3)) << 2);    // q_row1[c1^3]
    const int aR1  = gb + (col << 4);                // a lane whose c1 == col

    float q1A = bperm(aQ1A, qD), q1C = bperm(aQ1C, qD);
    float q2A  = swz<0, 8, 0x13>(qD);    // q_row2[c2]   (src = grpbit | 8 | (u&3))
    float q2C  = swz<3, 8, 0x13>(qD);    // q_row2[c2^3]
    float q3v0 = swz<0, 12, 0x10>(qD);   // q_row3[0..3] broadcast within group
    float q3v1 = swz<0, 13, 0x10>(qD);
    float q3v2 = swz<0, 14, 0x10>(qD);
    float q3v3 = swz<0, 15, 0x10>(qD);

    // ---- laplace-log-cdf accumulation (log2 units); pair trick C = -A ----
    float lpA[8] = {0,0,0,0,0,0,0,0};
    float lpC[8] = {0,0,0,0,0,0,0,0};
    const float* gw = &sG[wv][grp * 40];
#pragma unroll
    for (int r = 0; r < 8; ++r) {
        float4 g  = *(const float4*)(gw + r * 4);
        float b12 = fmaf(g.y, s1, g.z * s2);
        float m0  = g.x * rv;
        float m3  = g.w * rv;
        float t0  = fmaf(m0, -3.0f, b12);   // c0 = 0
        float t1  = b12 - m0;               // c0 = 1
#pragma unroll
        for (int j = 0; j < 8; ++j) {
            float tb = (j & 4) ? t1 : t0;
            float t  = fmaf(m3, (float)(2 * (j & 3) - 3), tb);   // x*LOG2E
            float at = -fabsf(t);
            float e  = EXP2(at);
            float lg = LOG2_(fmaf(e, -0.5f, 1.0f));
            float ng = at - 1.0f;
            bool neg = (t < 0.0f);
            lpA[j] += neg ? ng : lg;
            lpC[j] += neg ? lg : ng;
        }
    }

    // U-sums over c3 with q3 weights (C combo: c0C = 3-(j>>2), c3C = 3-(j&3))
    float UA0 = lpA[0]*q3v0 + lpA[1]*q3v1 + lpA[2]*q3v2 + lpA[3]*q3v3;
    float UA1 = lpA[4]*q3v0 + lpA[5]*q3v1 + lpA[6]*q3v2 + lpA[7]*q3v3;
    float UC3 = lpC[0]*q3v3 + lpC[1]*q3v2 + lpC[2]*q3v1 + lpC[3]*q3v0;
    float UC2 = lpC[4]*q3v3 + lpC[5]*q3v2 + lpC[6]*q3v1 + lpC[7]*q3v0;

    // ======== round 0 (groups = c0, in-lane) ========
    float JA, JC, Pin0, Pin1, Pin2, Pin3, Qin0, Qin1, Qin2, Qin3;
    {
        float preQ  = q1A * q2A;
        float preQC = q1C * q2C;
        float VA0 = UA0 * preQ,  VA1 = UA1 * preQ;    // -> ex cols 0,1
        float VC2 = UC2 * preQC, VC3 = UC3 * preQC;   // -> ex cols 2,3
        // reduce-scatter: pre-swap by bit0, then butterfly bits 1-3 (all DPP)
        bool bb = (u & 1);
        float S01 = (bb ? VA1 : VA0) + DPPX1(bb ? VA0 : VA1);
        float S23 = (bb ? VC3 : VC2) + DPPX1(bb ? VC2 : VC3);
        S01 += DPPX2(S01); S01 += DPPX4(S01); S01 += DPPX8(S01);
        S23 += DPPX2(S23); S23 += DPPX4(S23); S23 += DPPX8(S23);
        float exD = (col & 2) ? S23 : S01;   // component parity == col&1 == bit0
        float bl = fmaf(alm1, slqD, alpha * exD);
        slqD = (row == 0) ? bl : slqD;
        qD = softmax_all(slqD);
        float q0v0 = swz<0, 0, 0x10>(qD);
        float q0v1 = swz<0, 1, 0x10>(qD);
        float q0v2 = swz<0, 2, 0x10>(qD);
        float q0v3 = swz<0, 3, 0x10>(qD);
        JA = q0v0*UA0 + q0v1*UA1;            // reusable rounds 1-2
        JC = q0v3*UC3 + q0v2*UC2;
        Pin0 = lpA[0]*q0v0 + lpA[4]*q0v1;    // round-3 A-side per c3
        Pin1 = lpA[1]*q0v0 + lpA[5]*q0v1;
        Pin2 = lpA[2]*q0v0 + lpA[6]*q0v1;
        Pin3 = lpA[3]*q0v0 + lpA[7]*q0v1;
        Qin0 = lpC[3]*q0v3 + lpC[7]*q0v2;    // C-side: c3C=c -> j&3=3-c
        Qin1 = lpC[2]*q0v3 + lpC[6]*q0v2;
        Qin2 = lpC[1]*q0v3 + lpC[5]*q0v2;
        Qin3 = lpC[0]*q0v3 + lpC[4]*q0v2;
    }

    // ======== round 1 (groups = c1 = bits 2-3) ========
    {
        float SA = q2A * JA, SC = q2C * JC;
        SA += DPPX1(SA); SA += DPPX2(SA);           // sum over c2
        SC += DPPX1(SC); SC += DPPX2(SC);
        float T = SA + DPPX12(SC);                  // C of group c1^3 -> c1
        float exD = bperm(aR1, T);                  // ex[col]
        float bl = fmaf(alm1, slqD, alpha * exD);
        slqD = (row == 1) ? bl : slqD;
        qD = softmax_all(slqD);
        q1A = bperm(aQ1A, qD); q1C = bperm(aQ1C, qD);
    }

    // ======== round 2 (groups = c2 = bits 0-1) ========
    {
        float SA = q1A * JA, SC = q1C * JC;
        SA += DPPX4(SA); SA += DPPX8(SA);           // sum over c1
        SC += DPPX4(SC); SC += DPPX8(SC);
        float exD = SA + DPPX3(SC);                 // lands on own lane: c2 == col
        float bl = fmaf(alm1, slqD, alpha * exD);
        slqD = (row == 2) ? bl : slqD;
        qD = softmax_all(slqD);
        q2A = swz<0, 8, 0x13>(qD);
        q2C = swz<3, 8, 0x13>(qD);
    }

    // ======== round 3 (groups = c3, in-lane) ========
    {
        float WA = q1A * q2A, WC = q1C * q2C;
        float V0 = Pin0*WA + Qin0*WC;
        float V1 = Pin1*WA + Qin1*WC;
        float V2 = Pin2*WA + Qin2*WC;
        float V3 = Pin3*WA + Qin3*WC;
        bool bb = (u & 1);
        float S01 = (bb ? V1 : V0) + DPPX1(bb ? V0 : V1);
        float S23 = (bb ? V3 : V2) + DPPX1(bb ? V2 : V3);
        S01 += DPPX2(S01); S01 += DPPX4(S01); S01 += DPPX8(S01);
        S23 += DPPX2(S23); S23 += DPPX4(S23); S23 += DPPX8(S23);
        float exD = (col & 2) ? S23 : S01;
        float bl = fmaf(alm1, slqD, alpha * exD);
        slqD = (row == 3) ? bl : slqD;
    }

    // ---- single final renorm (all rows), then coalesced store ----
    {
        float m1 = fmaxf(slqD, DPPX1(slqD));
        float m  = fmaxf(m1, DPPX2(m1));
        slqD -= m;
    }
    if (valid) {
        out[(size_t)item * 16 + u] = slqD * LN2F;   // addr = ib*16+lane, coalesced
    }
}

extern "C" void kernel_launch(void* const* d_in, const int* in_sizes, int n_in,
                              void* d_out, int out_size, void* d_ws, size_t ws_size,
                              hipStream_t stream) {
    const float* log_qi = (const float*)d_in[0];
    const float* G      = (const float*)d_in[1];
    const float* rho    = (const float*)d_in[2];
    // d_in[3] = n_var — unused by the reference
    const float* alpha  = (const float*)d_in[4];
    float* out = (float*)d_out;

    const int N = in_sizes[2];                 // 32768 batch items
    const int blocks = (N + 15) / 16;          // 16 items per block (4 per wave)
    // TIMING PROBE: 3 identical idempotent launches; extra 2 dispatches add
    // exactly 2x T_kernel to dur_us. Output bit-identical to a single launch.
    for (int rep = 0; rep < 3; ++rep) {
        mfnet_layer_kernel<<<blocks, 256, 0, stream>>>(log_qi, G, rho, alpha, out, N);
    }
}

// Round 5
// 74.772 us; speedup vs baseline: 1.4044x; 1.4044x over previous
//
#include <hip/hip_runtime.h>

#define LOG2E 1.4426950408889634f
#define LN2F  0.6931471805599453f
#define RS5F  0.4472135954999579f  // 1/sqrt(5)

// single-instruction ds_swizzle (BitMode: src = ((lane & AND) | OR) ^ XOR, 32-lane groups)
template<int XOR, int OR, int AND>
__device__ __forceinline__ float swz(float v) {
    return __int_as_float(__builtin_amdgcn_ds_swizzle(
        __float_as_int(v), (XOR << 10) | (OR << 5) | AND));
}
#define EXP2(x)  __builtin_amdgcn_exp2f(x)   // raw v_exp_f32
#define LOG2_(x) __builtin_amdgcn_logf(x)    // raw v_log_f32
#define RCP_(x)  __builtin_amdgcn_rcpf(x)    // raw v_rcp_f32

// DPP cross-lane (full-rate VALU, no LDS pipe): XOR patterns within 16-lane rows.
template<int CTRL>
__device__ __forceinline__ float dppf(float v) {
    return __int_as_float(__builtin_amdgcn_update_dpp(
        0, __float_as_int(v), CTRL, 0xF, 0xF, true));
}
#define DPPX1(v)  dppf<0xB1>(v)    // quad_perm [1,0,3,2] : xor 1
#define DPPX2(v)  dppf<0x4E>(v)    // quad_perm [2,3,0,1] : xor 2
#define DPPX3(v)  dppf<0x1B>(v)    // quad_perm [3,2,1,0] : xor 3
#define DPPX8(v)  dppf<0x128>(v)   // row_ror:8           : xor 8 (within 16)
#define DPPHM(v)  dppf<0x141>(v)   // row_half_mirror     : xor 7
#define DPPRM(v)  dppf<0x140>(v)   // row_mirror          : xor 15
#define DPPX4(v)  DPPX3(DPPHM(v))  // xor 4 = xor7 then xor3
#define DPPX12(v) DPPX3(DPPRM(v))  // xor 12 = xor15 then xor3

__device__ __forceinline__ float bperm(int byte_addr, float v) {
    return __int_as_float(__builtin_amdgcn_ds_bpermute(byte_addr, __float_as_int(v)));
}

// 4 items per WAVE (16-lane item groups, 16 items per 256-block).
// Lane u = lane&15 holds state entry u (row=u>>2, col=u&3) — no mirror.
// Combo digits: c1 = u>>2 (bits 2-3), c2 = u&3 (bits 0-1); in-lane j in [0,8):
// c0A = j>>2 in {0,1}, c3A = j&3. C-combo = all-digit complement (c0C in {3,2}).
// 16 lanes x 8 j x {A,C} = 256 combos.
//
// LOG-PRODUCT REFORMULATION (round 4): laplace log-cdf in log2 units is
//   f(t) = log2(h) - 1,  h = (t<0) ? e : (2-e),  e = 2^(-|t|);
// complement side gets log2(2-h) - 1. Per-row sums become log2(prod of h)
// minus a constant 8; the constant shifts every log_p uniformly, ex-weights
// sum to 1, and the final per-row max-subtract removes uniform row shifts,
// so the -8 cancels EXACTLY and is dropped. 16 v_log_f32/lane instead of 64.
// Underflow: pos-side factors >= 1; product flushes only if sum of neg |t|
// in one 8-row slot exceeds ~126 (an ~11-sigma event) — negligible.
//
// Exactness of renorm scheme: per-row max shifted out at load; NO mid-round
// renorms; single final renorm.
__global__ __launch_bounds__(256, 4) void mfnet_layer_kernel(
    const float* __restrict__ log_qi,   // (N,4,4)
    const float* __restrict__ G,        // (N,8,4)
    const float* __restrict__ sqrt_2rho,// (N,)
    const float* __restrict__ alpha_ptr,// (1,)
    float* __restrict__ out,            // (N,4,4)
    int N)
{
    const int tid  = threadIdx.x;
    const int wv   = tid >> 6;
    const int lane = tid & 63;
    const int grp  = (lane >> 4) & 3;    // item within wave
    const int u    = lane & 15;
    const int ib   = blockIdx.x * 16 + wv * 4;

    // G staging: 4 items x 32 floats, item stride 40 (bases at banks 0/8/16/24
    // -> conflict-free 16B group-broadcast reads). Wave-local, no __syncthreads.
    __shared__ __align__(16) float sG[4][160];
    {
        size_t gidx = (size_t)ib * 32 + (size_t)(lane * 2);   // = ib*32 + 2*lane, coalesced
        size_t gmax = (size_t)N * 32 - 2;
        if (gidx > gmax) gidx = gmax;
        float2 gv = *(const float2*)(G + gidx);
        *(float2*)&sG[wv][grp * 40 + u * 2] = gv;
    }

    const int it0    = ib + grp;
    const bool valid = (it0 < N);
    const int item   = valid ? it0 : (N - 1);

    const float alpha = alpha_ptr[0];
    const float alm1  = 1.0f - alpha;

    const int col = u & 3;               // state col, also c2
    const int row = u >> 2;              // state row, also c1

    // symbols with LOG2E folded in (whole pipeline in log2 units)
    const float rv = sqrt_2rho[item] * (RS5F * LOG2E);
    const float s1 = rv * (float)(2 * row - 3);
    const float s2 = rv * (float)(2 * col - 3);

    // distributed state, log2 units; shift out each row's initial max
    float slqD = log_qi[(size_t)item * 16 + u] * LOG2E;   // addr = ib*16+lane, coalesced
    {
        float m1 = fmaxf(slqD, DPPX1(slqD));
        float m  = fmaxf(m1, DPPX2(m1));
        slqD -= m;
    }

    // softmax of all rows at once (4-lane packs) — DPP reductions
    auto softmax_all = [&](float s) {
        float e   = EXP2(s);
        float t   = e + DPPX1(e);
        float den = t + DPPX2(t);
        return e * RCP_(den);
    };
    float qD = softmax_all(slqD);

    // bpermute byte addresses (only where the source index needs shifted lane bits)
    const int gb   = (lane & 0x30) << 2;             // group-base byte address
    const int aQ1A = gb + ((4 + row) << 2);          // q_row1[c1]
    const int aQ1C = gb + ((4 + (row ^ 3)) << 2);    // q_row1[c1^3]
    const int aR1  = gb + (col << 4);                // a lane whose c1 == col

    float q1A = bperm(aQ1A, qD), q1C = bperm(aQ1C, qD);
    float q2A  = swz<0, 8, 0x13>(qD);    // q_row2[c2]   (src = grpbit | 8 | (u&3))
    float q2C  = swz<3, 8, 0x13>(qD);    // q_row2[c2^3]
    float q3v0 = swz<0, 12, 0x10>(qD);   // q_row3[0..3] broadcast within group
    float q3v1 = swz<0, 13, 0x10>(qD);
    float q3v2 = swz<0, 14, 0x10>(qD);
    float q3v3 = swz<0, 15, 0x10>(qD);

    // ---- laplace-log-cdf accumulation via h-products (log2 units) ----
    float prA[8] = {1,1,1,1,1,1,1,1};
    float prC[8] = {1,1,1,1,1,1,1,1};
    const float* gw = &sG[wv][grp * 40];
#pragma unroll
    for (int r = 0; r < 8; ++r) {
        float4 g  = *(const float4*)(gw + r * 4);
        float b12 = fmaf(g.y, s1, g.z * s2);
        float m0  = g.x * rv;
        float m3  = g.w * rv;
        float t0  = fmaf(m0, -3.0f, b12);   // c0 = 0
        float t1  = b12 - m0;               // c0 = 1
#pragma unroll
        for (int j = 0; j < 8; ++j) {
            float tb = (j & 4) ? t1 : t0;
            float t  = fmaf(m3, (float)(2 * (j & 3) - 3), tb);   // x*LOG2E
            float e  = EXP2(-fabsf(t));
            float e2 = 2.0f - e;
            bool neg = (t < 0.0f);
            prA[j] *= neg ? e : e2;
            prC[j] *= neg ? e2 : e;
        }
    }
    float lpA[8], lpC[8];
#pragma unroll
    for (int j = 0; j < 8; ++j) {
        lpA[j] = LOG2_(prA[j]);
        lpC[j] = LOG2_(prC[j]);
    }

    // U-sums over c3 with q3 weights (C combo: c0C = 3-(j>>2), c3C = 3-(j&3))
    float UA0 = lpA[0]*q3v0 + lpA[1]*q3v1 + lpA[2]*q3v2 + lpA[3]*q3v3;
    float UA1 = lpA[4]*q3v0 + lpA[5]*q3v1 + lpA[6]*q3v2 + lpA[7]*q3v3;
    float UC3 = lpC[0]*q3v3 + lpC[1]*q3v2 + lpC[2]*q3v1 + lpC[3]*q3v0;
    float UC2 = lpC[4]*q3v3 + lpC[5]*q3v2 + lpC[6]*q3v1 + lpC[7]*q3v0;

    // ======== round 0 (groups = c0, in-lane) ========
    float JA, JC, Pin0, Pin1, Pin2, Pin3, Qin0, Qin1, Qin2, Qin3;
    {
        float preQ  = q1A * q2A;
        float preQC = q1C * q2C;
        float VA0 = UA0 * preQ,  VA1 = UA1 * preQ;    // -> ex cols 0,1
        float VC2 = UC2 * preQC, VC3 = UC3 * preQC;   // -> ex cols 2,3
        // reduce-scatter: pre-swap by bit0, then butterfly bits 1-3 (all DPP)
        bool bb = (u & 1);
        float S01 = (bb ? VA1 : VA0) + DPPX1(bb ? VA0 : VA1);
        float S23 = (bb ? VC3 : VC2) + DPPX1(bb ? VC2 : VC3);
        S01 += DPPX2(S01); S01 += DPPX4(S01); S01 += DPPX8(S01);
        S23 += DPPX2(S23); S23 += DPPX4(S23); S23 += DPPX8(S23);
        float exD = (col & 2) ? S23 : S01;   // component parity == col&1 == bit0
        float bl = fmaf(alm1, slqD, alpha * exD);
        slqD = (row == 0) ? bl : slqD;
        qD = softmax_all(slqD);
        float q0v0 = swz<0, 0, 0x10>(qD);
        float q0v1 = swz<0, 1, 0x10>(qD);
        float q0v2 = swz<0, 2, 0x10>(qD);
        float q0v3 = swz<0, 3, 0x10>(qD);
        JA = q0v0*UA0 + q0v1*UA1;            // reusable rounds 1-2
        JC = q0v3*UC3 + q0v2*UC2;
        Pin0 = lpA[0]*q0v0 + lpA[4]*q0v1;    // round-3 A-side per c3
        Pin1 = lpA[1]*q0v0 + lpA[5]*q0v1;
        Pin2 = lpA[2]*q0v0 + lpA[6]*q0v1;
        Pin3 = lpA[3]*q0v0 + lpA[7]*q0v1;
        Qin0 = lpC[3]*q0v3 + lpC[7]*q0v2;    // C-side: c3C=c -> j&3=3-c
        Qin1 = lpC[2]*q0v3 + lpC[6]*q0v2;
        Qin2 = lpC[1]*q0v3 + lpC[5]*q0v2;
        Qin3 = lpC[0]*q0v3 + lpC[4]*q0v2;
    }

    // ======== round 1 (groups = c1 = bits 2-3) ========
    {
        float SA = q2A * JA, SC = q2C * JC;
        SA += DPPX1(SA); SA += DPPX2(SA);           // sum over c2
        SC += DPPX1(SC); SC += DPPX2(SC);
        float T = SA + DPPX12(SC);                  // C of group c1^3 -> c1
        float exD = bperm(aR1, T);                  // ex[col]
        float bl = fmaf(alm1, slqD, alpha * exD);
        slqD = (row == 1) ? bl : slqD;
        qD = softmax_all(slqD);
        q1A = bperm(aQ1A, qD); q1C = bperm(aQ1C, qD);
    }

    // ======== round 2 (groups = c2 = bits 0-1) ========
    {
        float SA = q1A * JA, SC = q1C * JC;
        SA += DPPX4(SA); SA += DPPX8(SA);           // sum over c1
        SC += DPPX4(SC); SC += DPPX8(SC);
        float exD = SA + DPPX3(SC);                 // lands on own lane: c2 == col
        float bl = fmaf(alm1, slqD, alpha * exD);
        slqD = (row == 2) ? bl : slqD;
        qD = softmax_all(slqD);
        q2A = swz<0, 8, 0x13>(qD);
        q2C = swz<3, 8, 0x13>(qD);
    }

    // ======== round 3 (groups = c3, in-lane) ========
    {
        float WA = q1A * q2A, WC = q1C * q2C;
        float V0 = Pin0*WA + Qin0*WC;
        float V1 = Pin1*WA + Qin1*WC;
        float V2 = Pin2*WA + Qin2*WC;
        float V3 = Pin3*WA + Qin3*WC;
        bool bb = (u & 1);
        float S01 = (bb ? V1 : V0) + DPPX1(bb ? V0 : V1);
        float S23 = (bb ? V3 : V2) + DPPX1(bb ? V2 : V3);
        S01 += DPPX2(S01); S01 += DPPX4(S01); S01 += DPPX8(S01);
        S23 += DPPX2(S23); S23 += DPPX4(S23); S23 += DPPX8(S23);
        float exD = (col & 2) ? S23 : S01;
        float bl = fmaf(alm1, slqD, alpha * exD);
        slqD = (row == 3) ? bl : slqD;
    }

    // ---- single final renorm (all rows), then coalesced store ----
    {
        float m1 = fmaxf(slqD, DPPX1(slqD));
        float m  = fmaxf(m1, DPPX2(m1));
        slqD -= m;
    }
    if (valid) {
        out[(size_t)item * 16 + u] = slqD * LN2F;   // addr = ib*16+lane, coalesced
    }
}

extern "C" void kernel_launch(void* const* d_in, const int* in_sizes, int n_in,
                              void* d_out, int out_size, void* d_ws, size_t ws_size,
                              hipStream_t stream) {
    const float* log_qi = (const float*)d_in[0];
    const float* G      = (const float*)d_in[1];
    const float* rho    = (const float*)d_in[2];
    // d_in[3] = n_var — unused by the reference
    const float* alpha  = (const float*)d_in[4];
    float* out = (float*)d_out;

    const int N = in_sizes[2];                 // 32768 batch items
    const int blocks = (N + 15) / 16;          // 16 items per block (4 per wave)
    mfnet_layer_kernel<<<blocks, 256, 0, stream>>>(log_qi, G, rho, alpha, out, N);
}

// Round 7
// 74.192 us; speedup vs baseline: 1.4154x; 1.0078x over previous
//
#include <hip/hip_runtime.h>

#define LOG2E 1.4426950408889634f
#define LN2F  0.6931471805599453f
#define RS5F  0.4472135954999579f  // 1/sqrt(5)

// single-instruction ds_swizzle (BitMode: src = ((lane & AND) | OR) ^ XOR, 32-lane groups)
template<int XOR, int OR, int AND>
__device__ __forceinline__ float swz(float v) {
    return __int_as_float(__builtin_amdgcn_ds_swizzle(
        __float_as_int(v), (XOR << 10) | (OR << 5) | AND));
}
#define EXP2(x)  __builtin_amdgcn_exp2f(x)   // raw v_exp_f32
#define LOG2_(x) __builtin_amdgcn_logf(x)    // raw v_log_f32
#define RCP_(x)  __builtin_amdgcn_rcpf(x)    // raw v_rcp_f32

// DPP cross-lane (full-rate VALU, no LDS pipe): XOR patterns within 16-lane rows.
template<int CTRL>
__device__ __forceinline__ float dppf(float v) {
    return __int_as_float(__builtin_amdgcn_update_dpp(
        0, __float_as_int(v), CTRL, 0xF, 0xF, true));
}
#define DPPX1(v)  dppf<0xB1>(v)    // quad_perm [1,0,3,2] : xor 1
#define DPPX2(v)  dppf<0x4E>(v)    // quad_perm [2,3,0,1] : xor 2
#define DPPX3(v)  dppf<0x1B>(v)    // quad_perm [3,2,1,0] : xor 3
#define DPPX8(v)  dppf<0x128>(v)   // row_ror:8           : xor 8 (within 16)
#define DPPHM(v)  dppf<0x141>(v)   // row_half_mirror     : xor 7
#define DPPRM(v)  dppf<0x140>(v)   // row_mirror          : xor 15
#define DPPX4(v)  DPPX3(DPPHM(v))  // xor 4 = xor7 then xor3
#define DPPX12(v) DPPX3(DPPRM(v))  // xor 12 = xor15 then xor3

__device__ __forceinline__ float bperm(int byte_addr, float v) {
    return __int_as_float(__builtin_amdgcn_ds_bpermute(byte_addr, __float_as_int(v)));
}

// 4 items per WAVE (16-lane item groups, 16 items per 256-block).
// Lane u = lane&15 holds state entry u (row=u>>2, col=u&3) — no mirror.
// Combo digits: c1 = u>>2 (bits 2-3), c2 = u&3 (bits 0-1); in-lane j in [0,8):
// c0A = j>>2 in {0,1}, c3A = j&3. C-combo = all-digit complement (c0C in {3,2}).
// 16 lanes x 8 j x {A,C} = 256 combos.
//
// LOG-PRODUCT REFORMULATION (round 4, VERIFIED): laplace log-cdf in log2
// units is f(t) = log2(h) - 1,  h = (t<0) ? e : (2-e),  e = 2^(-|t|);
// complement side gets log2(2-h) - 1. Per-row sums become log2(prod of h)
// minus a constant 8; the constant shifts every log_p uniformly, ex-weights
// sum to 1, and the final per-row max-subtract removes uniform row shifts,
// so the -8 cancels EXACTLY and is dropped. 16 v_log_f32/lane instead of 64.
//
// NUMERICS WARNING (round-5 failure, do NOT re-attempt): folding the select
// as w = copysign(1-e, t), factor = 1±w is WRONG — fl(1-e) == 1.0 for
// e < 2^-25 (|t| > ~17, a ~2-sigma event), so the small factor collapses to
// exactly 0 -> log2 = -inf -> NaN. The tiny factor must stay the raw e.
//
// Exactness of renorm scheme: per-row max shifted out at load; NO mid-round
// renorms (non-updated rows have max 0, softmax is shift-invariant, blend
// inputs untouched since load); single final renorm.
__global__ __launch_bounds__(256, 4) void mfnet_layer_kernel(
    const float* __restrict__ log_qi,   // (N,4,4)
    const float* __restrict__ G,        // (N,8,4)
    const float* __restrict__ sqrt_2rho,// (N,)
    const float* __restrict__ alpha_ptr,// (1,)
    float* __restrict__ out,            // (N,4,4)
    int N)
{
    const int tid  = threadIdx.x;
    const int wv   = tid >> 6;
    const int lane = tid & 63;
    const int grp  = (lane >> 4) & 3;    // item within wave
    const int u    = lane & 15;
    const int ib   = blockIdx.x * 16 + wv * 4;

    // G staging: 4 items x 32 floats, item stride 40 (bases at banks 0/8/16/24
    // -> conflict-free 16B group-broadcast reads). Wave-local, no __syncthreads.
    __shared__ __align__(16) float sG[4][160];
    {
        size_t gidx = (size_t)ib * 32 + (size_t)(lane * 2);   // = ib*32 + 2*lane, coalesced
        size_t gmax = (size_t)N * 32 - 2;
        if (gidx > gmax) gidx = gmax;
        float2 gv = *(const float2*)(G + gidx);
        *(float2*)&sG[wv][grp * 40 + u * 2] = gv;
    }

    const int it0    = ib + grp;
    const bool valid = (it0 < N);
    const int item   = valid ? it0 : (N - 1);

    const float alpha = alpha_ptr[0];
    const float alm1  = 1.0f - alpha;

    const int col = u & 3;               // state col, also c2
    const int row = u >> 2;              // state row, also c1

    // symbols with LOG2E folded in (whole pipeline in log2 units)
    const float rv = sqrt_2rho[item] * (RS5F * LOG2E);
    const float s1 = rv * (float)(2 * row - 3);
    const float s2 = rv * (float)(2 * col - 3);

    // distributed state, log2 units; shift out each row's initial max
    float slqD = log_qi[(size_t)item * 16 + u] * LOG2E;   // addr = ib*16+lane, coalesced
    {
        float m1 = fmaxf(slqD, DPPX1(slqD));
        float m  = fmaxf(m1, DPPX2(m1));
        slqD -= m;
    }

    // softmax of all rows at once (4-lane packs) — DPP reductions
    auto softmax_all = [&](float s) {
        float e   = EXP2(s);
        float t   = e + DPPX1(e);
        float den = t + DPPX2(t);
        return e * RCP_(den);
    };
    float qD = softmax_all(slqD);

    // bpermute byte addresses (only where the source index needs shifted lane bits)
    const int gb   = (lane & 0x30) << 2;             // group-base byte address
    const int aQ1A = gb + ((4 + row) << 2);          // q_row1[c1]
    const int aQ1C = gb + ((4 + (row ^ 3)) << 2);    // q_row1[c1^3]
    const int aR1  = gb + (col << 4);                // a lane whose c1 == col

    float q1A = bperm(aQ1A, qD), q1C = bperm(aQ1C, qD);
    float q2A  = swz<0, 8, 0x13>(qD);    // q_row2[c2]   (src = grpbit | 8 | (u&3))
    float q2C  = swz<3, 8, 0x13>(qD);    // q_row2[c2^3]
    float q3v0 = swz<0, 12, 0x10>(qD);   // q_row3[0..3] broadcast within group
    float q3v1 = swz<0, 13, 0x10>(qD);
    float q3v2 = swz<0, 14, 0x10>(qD);
    float q3v3 = swz<0, 15, 0x10>(qD);

    // ---- laplace-log-cdf accumulation via h-products (log2 units) ----
    float prA[8] = {1,1,1,1,1,1,1,1};
    float prC[8] = {1,1,1,1,1,1,1,1};
    const float* gw = &sG[wv][grp * 40];
#pragma unroll
    for (int r = 0; r < 8; ++r) {
        float4 g  = *(const float4*)(gw + r * 4);
        float b12 = fmaf(g.y, s1, g.z * s2);
        float m0  = g.x * rv;
        float m3  = g.w * rv;
        float t0  = fmaf(m0, -3.0f, b12);   // c0 = 0
        float t1  = b12 - m0;               // c0 = 1
#pragma unroll
        for (int j = 0; j < 8; ++j) {
            float tb = (j & 4) ? t1 : t0;
            float t  = fmaf(m3, (float)(2 * (j & 3) - 3), tb);   // x*LOG2E
            float e  = EXP2(-fabsf(t));
            float e2 = 2.0f - e;
            bool neg = (t < 0.0f);
            prA[j] *= neg ? e : e2;
            prC[j] *= neg ? e2 : e;
        }
    }
    float lpA[8], lpC[8];
#pragma unroll
    for (int j = 0; j < 8; ++j) {
        lpA[j] = LOG2_(prA[j]);
        lpC[j] = LOG2_(prC[j]);
    }

    // U-sums over c3 with q3 weights (C combo: c0C = 3-(j>>2), c3C = 3-(j&3))
    float UA0 = lpA[0]*q3v0 + lpA[1]*q3v1 + lpA[2]*q3v2 + lpA[3]*q3v3;
    float UA1 = lpA[4]*q3v0 + lpA[5]*q3v1 + lpA[6]*q3v2 + lpA[7]*q3v3;
    float UC3 = lpC[0]*q3v3 + lpC[1]*q3v2 + lpC[2]*q3v1 + lpC[3]*q3v0;
    float UC2 = lpC[4]*q3v3 + lpC[5]*q3v2 + lpC[6]*q3v1 + lpC[7]*q3v0;

    // ======== round 0 (groups = c0, in-lane) ========
    float JA, JC, Pin0, Pin1, Pin2, Pin3, Qin0, Qin1, Qin2, Qin3;
    {
        float preQ  = q1A * q2A;
        float preQC = q1C * q2C;
        float VA0 = UA0 * preQ,  VA1 = UA1 * preQ;    // -> ex cols 0,1
        float VC2 = UC2 * preQC, VC3 = UC3 * preQC;   // -> ex cols 2,3
        // reduce-scatter: pre-swap by bit0, then butterfly bits 1-3 (all DPP)
        bool bb = (u & 1);
        float S01 = (bb ? VA1 : VA0) + DPPX1(bb ? VA0 : VA1);
        float S23 = (bb ? VC3 : VC2) + DPPX1(bb ? VC2 : VC3);
        S01 += DPPX2(S01); S01 += DPPX4(S01); S01 += DPPX8(S01);
        S23 += DPPX2(S23); S23 += DPPX4(S23); S23 += DPPX8(S23);
        float exD = (col & 2) ? S23 : S01;   // component parity == col&1 == bit0
        float bl = fmaf(alm1, slqD, alpha * exD);
        slqD = (row == 0) ? bl : slqD;
        qD = softmax_all(slqD);
        float q0v0 = swz<0, 0, 0x10>(qD);
        float q0v1 = swz<0, 1, 0x10>(qD);
        float q0v2 = swz<0, 2, 0x10>(qD);
        float q0v3 = swz<0, 3, 0x10>(qD);
        JA = q0v0*UA0 + q0v1*UA1;            // reusable rounds 1-2
        JC = q0v3*UC3 + q0v2*UC2;
        Pin0 = lpA[0]*q0v0 + lpA[4]*q0v1;    // round-3 A-side per c3
        Pin1 = lpA[1]*q0v0 + lpA[5]*q0v1;
        Pin2 = lpA[2]*q0v0 + lpA[6]*q0v1;
        Pin3 = lpA[3]*q0v0 + lpA[7]*q0v1;
        Qin0 = lpC[3]*q0v3 + lpC[7]*q0v2;    // C-side: c3C=c -> j&3=3-c
        Qin1 = lpC[2]*q0v3 + lpC[6]*q0v2;
        Qin2 = lpC[1]*q0v3 + lpC[5]*q0v2;
        Qin3 = lpC[0]*q0v3 + lpC[4]*q0v2;
    }

    // ======== round 1 (groups = c1 = bits 2-3) ========
    {
        float SA = q2A * JA, SC = q2C * JC;
        SA += DPPX1(SA); SA += DPPX2(SA);           // sum over c2
        SC += DPPX1(SC); SC += DPPX2(SC);
        float T = SA + DPPX12(SC);                  // C of group c1^3 -> c1
        float exD = bperm(aR1, T);                  // ex[col]
        float bl = fmaf(alm1, slqD, alpha * exD);
        slqD = (row == 1) ? bl : slqD;
        qD = softmax_all(slqD);
        q1A = bperm(aQ1A, qD); q1C = bperm(aQ1C, qD);
    }

    // ======== round 2 (groups = c2 = bits 0-1) ========
    {
        float SA = q1A * JA, SC = q1C * JC;
        SA += DPPX4(SA); SA += DPPX8(SA);           // sum over c1
        SC += DPPX4(SC); SC += DPPX8(SC);
        float exD = SA + DPPX3(SC);                 // lands on own lane: c2 == col
        float bl = fmaf(alm1, slqD, alpha * exD);
        slqD = (row == 2) ? bl : slqD;
        qD = softmax_all(slqD);
        q2A = swz<0, 8, 0x13>(qD);
        q2C = swz<3, 8, 0x13>(qD);
    }

    // ======== round 3 (groups = c3, in-lane) ========
    {
        float WA = q1A * q2A, WC = q1C * q2C;
        float V0 = Pin0*WA + Qin0*WC;
        float V1 = Pin1*WA + Qin1*WC;
        float V2 = Pin2*WA + Qin2*WC;
        float V3 = Pin3*WA + Qin3*WC;
        bool bb = (u & 1);
        float S01 = (bb ? V1 : V0) + DPPX1(bb ? V0 : V1);
        float S23 = (bb ? V3 : V2) + DPPX1(bb ? V2 : V3);
        S01 += DPPX2(S01); S01 += DPPX4(S01); S01 += DPPX8(S01);
        S23 += DPPX2(S23); S23 += DPPX4(S23); S23 += DPPX8(S23);
        float exD = (col & 2) ? S23 : S01;
        float bl = fmaf(alm1, slqD, alpha * exD);
        slqD = (row == 3) ? bl : slqD;
    }

    // ---- single final renorm (all rows), then coalesced store ----
    {
        float m1 = fmaxf(slqD, DPPX1(slqD));
        float m  = fmaxf(m1, DPPX2(m1));
        slqD -= m;
    }
    if (valid) {
        out[(size_t)item * 16 + u] = slqD * LN2F;   // addr = ib*16+lane, coalesced
    }
}

extern "C" void kernel_launch(void* const* d_in, const int* in_sizes, int n_in,
                              void* d_out, int out_size, void* d_ws, size_t ws_size,
                              hipStream_t stream) {
    const float* log_qi = (const float*)d_in[0];
    const float* G      = (const float*)d_in[1];
    const float* rho    = (const float*)d_in[2];
    // d_in[3] = n_var — unused by the reference
    const float* alpha  = (const float*)d_in[4];
    float* out = (float*)d_out;

    const int N = in_sizes[2];                 // 32768 batch items
    const int blocks = (N + 15) / 16;          // 16 items per block (4 per wave)
    mfnet_layer_kernel<<<blocks, 256, 0, stream>>>(log_qi, G, rho, alpha, out, N);
}

// Round 8
// 73.734 us; speedup vs baseline: 1.4242x; 1.0062x over previous
//
#include <hip/hip_runtime.h>

#define LOG2E 1.4426950408889634f
#define LN2F  0.6931471805599453f
#define RS5F  0.4472135954999579f  // 1/sqrt(5)

typedef float v2f __attribute__((ext_vector_type(2)));

// single-instruction ds_swizzle (BitMode: src = ((lane & AND) | OR) ^ XOR, 32-lane groups)
template<int XOR, int OR, int AND>
__device__ __forceinline__ float swz(float v) {
    return __int_as_float(__builtin_amdgcn_ds_swizzle(
        __float_as_int(v), (XOR << 10) | (OR << 5) | AND));
}
#define EXP2(x)  __builtin_amdgcn_exp2f(x)   // raw v_exp_f32
#define LOG2_(x) __builtin_amdgcn_logf(x)    // raw v_log_f32
#define RCP_(x)  __builtin_amdgcn_rcpf(x)    // raw v_rcp_f32

// DPP cross-lane (full-rate VALU, no LDS pipe): XOR patterns within 16-lane rows.
template<int CTRL>
__device__ __forceinline__ float dppf(float v) {
    return __int_as_float(__builtin_amdgcn_update_dpp(
        0, __float_as_int(v), CTRL, 0xF, 0xF, true));
}
#define DPPX1(v)  dppf<0xB1>(v)    // quad_perm [1,0,3,2] : xor 1
#define DPPX2(v)  dppf<0x4E>(v)    // quad_perm [2,3,0,1] : xor 2
#define DPPX3(v)  dppf<0x1B>(v)    // quad_perm [3,2,1,0] : xor 3
#define DPPX8(v)  dppf<0x128>(v)   // row_ror:8           : xor 8 (within 16)
#define DPPHM(v)  dppf<0x141>(v)   // row_half_mirror     : xor 7
#define DPPRM(v)  dppf<0x140>(v)   // row_mirror          : xor 15
#define DPPX4(v)  DPPX3(DPPHM(v))  // xor 4 = xor7 then xor3
#define DPPX12(v) DPPX3(DPPRM(v))  // xor 12 = xor15 then xor3

__device__ __forceinline__ float bperm(int byte_addr, float v) {
    return __int_as_float(__builtin_amdgcn_ds_bpermute(byte_addr, __float_as_int(v)));
}

// 4 items per WAVE (16-lane item groups, 16 items per 256-block).
// Lane u = lane&15 holds state entry u (row=u>>2, col=u&3) — no mirror.
// Combo digits: c1 = u>>2 (bits 2-3), c2 = u&3 (bits 0-1); in-lane j in [0,8):
// c0A = j>>2 in {0,1}, c3A = j&3. C-combo = all-digit complement (c0C in {3,2}).
// 16 lanes x 8 j x {A,C} = 256 combos.
//
// LOG-PRODUCT REFORMULATION (round 4, VERIFIED): laplace log-cdf in log2
// units is f(t) = log2(h) - 1,  h = (t<0) ? e : (2-e),  e = 2^(-|t|);
// complement side gets log2(2-h) - 1. Per-row sums become log2(prod of h);
// the dropped constant shifts every log_p uniformly, ex-weights sum to 1,
// and the final per-row max-subtract removes uniform row shifts, so it
// cancels EXACTLY. 16 v_log_f32/lane instead of 64.
//
// PACKED F32 (round 7): j-pairs (2m,2m+1) share tb and differ only in the
// m3 coefficient -> t-pair via one v_pk_fma_f32, e2-pair via one packed sub,
// pr updates via v_pk_mul_f32. Packed ops are bit-identical IEEE to the
// scalar pair; exp2/cmp/cndmask stay scalar. All vector indices static.
//
// NUMERICS WARNING (round-5 failure, do NOT re-attempt): folding the select
// as w = copysign(1-e, t), factor = 1±w is WRONG — fl(1-e) == 1.0 for
// e < 2^-25 (|t| > ~17, a ~2-sigma event), so the small factor collapses to
// exactly 0 -> log2 = -inf -> NaN. The tiny factor must stay the raw e.
//
// Exactness of renorm scheme: per-row max shifted out at load; NO mid-round
// renorms (non-updated rows have max 0, softmax is shift-invariant, blend
// inputs untouched since load); single final renorm.
__global__ __launch_bounds__(256, 4) void mfnet_layer_kernel(
    const float* __restrict__ log_qi,   // (N,4,4)
    const float* __restrict__ G,        // (N,8,4)
    const float* __restrict__ sqrt_2rho,// (N,)
    const float* __restrict__ alpha_ptr,// (1,)
    float* __restrict__ out,            // (N,4,4)
    int N)
{
    const int tid  = threadIdx.x;
    const int wv   = tid >> 6;
    const int lane = tid & 63;
    const int grp  = (lane >> 4) & 3;    // item within wave
    const int u    = lane & 15;
    const int ib   = blockIdx.x * 16 + wv * 4;

    // G staging: 4 items x 32 floats, item stride 40 (bases at banks 0/8/16/24
    // -> conflict-free 16B group-broadcast reads). Wave-local, no __syncthreads.
    __shared__ __align__(16) float sG[4][160];
    {
        size_t gidx = (size_t)ib * 32 + (size_t)(lane * 2);   // = ib*32 + 2*lane, coalesced
        size_t gmax = (size_t)N * 32 - 2;
        if (gidx > gmax) gidx = gmax;
        float2 gv = *(const float2*)(G + gidx);
        *(float2*)&sG[wv][grp * 40 + u * 2] = gv;
    }

    const int it0    = ib + grp;
    const bool valid = (it0 < N);
    const int item   = valid ? it0 : (N - 1);

    const float alpha = alpha_ptr[0];
    const float alm1  = 1.0f - alpha;

    const int col = u & 3;               // state col, also c2
    const int row = u >> 2;              // state row, also c1

    // symbols with LOG2E folded in (whole pipeline in log2 units)
    const float rv = sqrt_2rho[item] * (RS5F * LOG2E);
    const float s1 = rv * (float)(2 * row - 3);
    const float s2 = rv * (float)(2 * col - 3);

    // distributed state, log2 units; shift out each row's initial max
    float slqD = log_qi[(size_t)item * 16 + u] * LOG2E;   // addr = ib*16+lane, coalesced
    {
        float m1 = fmaxf(slqD, DPPX1(slqD));
        float m  = fmaxf(m1, DPPX2(m1));
        slqD -= m;
    }

    // softmax of all rows at once (4-lane packs) — DPP reductions
    auto softmax_all = [&](float s) {
        float e   = EXP2(s);
        float t   = e + DPPX1(e);
        float den = t + DPPX2(t);
        return e * RCP_(den);
    };
    float qD = softmax_all(slqD);

    // bpermute byte addresses (only where the source index needs shifted lane bits)
    const int gb   = (lane & 0x30) << 2;             // group-base byte address
    const int aQ1A = gb + ((4 + row) << 2);          // q_row1[c1]
    const int aQ1C = gb + ((4 + (row ^ 3)) << 2);    // q_row1[c1^3]
    const int aR1  = gb + (col << 4);                // a lane whose c1 == col

    float q1A = bperm(aQ1A, qD), q1C = bperm(aQ1C, qD);
    float q2A  = swz<0, 8, 0x13>(qD);    // q_row2[c2]   (src = grpbit | 8 | (u&3))
    float q2C  = swz<3, 8, 0x13>(qD);    // q_row2[c2^3]
    float q3v0 = swz<0, 12, 0x10>(qD);   // q_row3[0..3] broadcast within group
    float q3v1 = swz<0, 13, 0x10>(qD);
    float q3v2 = swz<0, 14, 0x10>(qD);
    float q3v3 = swz<0, 15, 0x10>(qD);

    // ---- laplace-log-cdf accumulation via h-products (packed f32 pairs) ----
    // pair m holds j = 2m, 2m+1:  tb = (m>=2) ? t1 : t0;  m3 coeffs per pair:
    // m=0:{-3,-1}  m=1:{1,3}  m=2:{-3,-1}  m=3:{1,3}
    v2f prA[4] = {{1,1},{1,1},{1,1},{1,1}};
    v2f prC[4] = {{1,1},{1,1},{1,1},{1,1}};
    const float* gw = &sG[wv][grp * 40];
#pragma unroll
    for (int r = 0; r < 8; ++r) {
        float4 g  = *(const float4*)(gw + r * 4);
        float b12 = fmaf(g.y, s1, g.z * s2);
        float m0  = g.x * rv;
        float m3  = g.w * rv;
        float t0  = fmaf(m0, -3.0f, b12);   // c0 = 0
        float t1  = b12 - m0;               // c0 = 1
#pragma unroll
        for (int m = 0; m < 4; ++m) {
            float tb = (m & 2) ? t1 : t0;
            v2f cc; cc.x = (m & 1) ? 1.0f : -3.0f;
                    cc.y = (m & 1) ? 3.0f : -1.0f;
            v2f m3v; m3v.x = m3; m3v.y = m3;
            v2f tbv; tbv.x = tb; tbv.y = tb;
            v2f t = m3v * cc + tbv;               // v_pk_fma_f32 (contracted)
            v2f e; e.x = EXP2(-fabsf(t.x));       // scalar trans
                   e.y = EXP2(-fabsf(t.y));
            v2f e2 = 2.0f - e;                    // packed sub
            bool nx = (t.x < 0.0f), ny = (t.y < 0.0f);
            v2f fA; fA.x = nx ? e.x  : e2.x;  fA.y = ny ? e.y  : e2.y;
            v2f fC; fC.x = nx ? e2.x : e.x;   fC.y = ny ? e2.y : e.y;
            prA[m] *= fA;                         // v_pk_mul_f32
            prC[m] *= fC;
        }
    }
    float lpA[8], lpC[8];
#pragma unroll
    for (int m = 0; m < 4; ++m) {
        lpA[2*m]   = LOG2_(prA[m].x);
        lpA[2*m+1] = LOG2_(prA[m].y);
        lpC[2*m]   = LOG2_(prC[m].x);
        lpC[2*m+1] = LOG2_(prC[m].y);
    }

    // U-sums over c3 with q3 weights (C combo: c0C = 3-(j>>2), c3C = 3-(j&3))
    float UA0 = lpA[0]*q3v0 + lpA[1]*q3v1 + lpA[2]*q3v2 + lpA[3]*q3v3;
    float UA1 = lpA[4]*q3v0 + lpA[5]*q3v1 + lpA[6]*q3v2 + lpA[7]*q3v3;
    float UC3 = lpC[0]*q3v3 + lpC[1]*q3v2 + lpC[2]*q3v1 + lpC[3]*q3v0;
    float UC2 = lpC[4]*q3v3 + lpC[5]*q3v2 + lpC[6]*q3v1 + lpC[7]*q3v0;

    // ======== round 0 (groups = c0, in-lane) ========
    float JA, JC, Pin0, Pin1, Pin2, Pin3, Qin0, Qin1, Qin2, Qin3;
    {
        float preQ  = q1A * q2A;
        float preQC = q1C * q2C;
        float VA0 = UA0 * preQ,  VA1 = UA1 * preQ;    // -> ex cols 0,1
        float VC2 = UC2 * preQC, VC3 = UC3 * preQC;   // -> ex cols 2,3
        // reduce-scatter: pre-swap by bit0, then butterfly bits 1-3 (all DPP)
        bool bb = (u & 1);
        float S01 = (bb ? VA1 : VA0) + DPPX1(bb ? VA0 : VA1);
        float S23 = (bb ? VC3 : VC2) + DPPX1(bb ? VC2 : VC3);
        S01 += DPPX2(S01); S01 += DPPX4(S01); S01 += DPPX8(S01);
        S23 += DPPX2(S23); S23 += DPPX4(S23); S23 += DPPX8(S23);
        float exD = (col & 2) ? S23 : S01;   // component parity == col&1 == bit0
        float bl = fmaf(alm1, slqD, alpha * exD);
        slqD = (row == 0) ? bl : slqD;
        qD = softmax_all(slqD);
        float q0v0 = swz<0, 0, 0x10>(qD);
        float q0v1 = swz<0, 1, 0x10>(qD);
        float q0v2 = swz<0, 2, 0x10>(qD);
        float q0v3 = swz<0, 3, 0x10>(qD);
        JA = q0v0*UA0 + q0v1*UA1;            // reusable rounds 1-2
        JC = q0v3*UC3 + q0v2*UC2;
        Pin0 = lpA[0]*q0v0 + lpA[4]*q0v1;    // round-3 A-side per c3
        Pin1 = lpA[1]*q0v0 + lpA[5]*q0v1;
        Pin2 = lpA[2]*q0v0 + lpA[6]*q0v1;
        Pin3 = lpA[3]*q0v0 + lpA[7]*q0v1;
        Qin0 = lpC[3]*q0v3 + lpC[7]*q0v2;    // C-side: c3C=c -> j&3=3-c
        Qin1 = lpC[2]*q0v3 + lpC[6]*q0v2;
        Qin2 = lpC[1]*q0v3 + lpC[5]*q0v2;
        Qin3 = lpC[0]*q0v3 + lpC[4]*q0v2;
    }

    // ======== round 1 (groups = c1 = bits 2-3) ========
    {
        float SA = q2A * JA, SC = q2C * JC;
        SA += DPPX1(SA); SA += DPPX2(SA);           // sum over c2
        SC += DPPX1(SC); SC += DPPX2(SC);
        float T = SA + DPPX12(SC);                  // C of group c1^3 -> c1
        float exD = bperm(aR1, T);                  // ex[col]
        float bl = fmaf(alm1, slqD, alpha * exD);
        slqD = (row == 1) ? bl : slqD;
        qD = softmax_all(slqD);
        q1A = bperm(aQ1A, qD); q1C = bperm(aQ1C, qD);
    }

    // ======== round 2 (groups = c2 = bits 0-1) ========
    {
        float SA = q1A * JA, SC = q1C * JC;
        SA += DPPX4(SA); SA += DPPX8(SA);           // sum over c1
        SC += DPPX4(SC); SC += DPPX8(SC);
        float exD = SA + DPPX3(SC);                 // lands on own lane: c2 == col
        float bl = fmaf(alm1, slqD, alpha * exD);
        slqD = (row == 2) ? bl : slqD;
        qD = softmax_all(slqD);
        q2A = swz<0, 8, 0x13>(qD);
        q2C = swz<3, 8, 0x13>(qD);
    }

    // ======== round 3 (groups = c3, in-lane) ========
    {
        float WA = q1A * q2A, WC = q1C * q2C;
        float V0 = Pin0*WA + Qin0*WC;
        float V1 = Pin1*WA + Qin1*WC;
        float V2 = Pin2*WA + Qin2*WC;
        float V3 = Pin3*WA + Qin3*WC;
        bool bb = (u & 1);
        float S01 = (bb ? V1 : V0) + DPPX1(bb ? V0 : V1);
        float S23 = (bb ? V3 : V2) + DPPX1(bb ? V2 : V3);
        S01 += DPPX2(S01); S01 += DPPX4(S01); S01 += DPPX8(S01);
        S23 += DPPX2(S23); S23 += DPPX4(S23); S23 += DPPX8(S23);
        float exD = (col & 2) ? S23 : S01;
        float bl = fmaf(alm1, slqD, alpha * exD);
        slqD = (row == 3) ? bl : slqD;
    }

    // ---- single final renorm (all rows), then coalesced store ----
    {
        float m1 = fmaxf(slqD, DPPX1(slqD));
        float m  = fmaxf(m1, DPPX2(m1));
        slqD -= m;
    }
    if (valid) {
        out[(size_t)item * 16 + u] = slqD * LN2F;   // addr = ib*16+lane, coalesced
    }
}

extern "C" void kernel_launch(void* const* d_in, const int* in_sizes, int n_in,
                              void* d_out, int out_size, void* d_ws, size_t ws_size,
                              hipStream_t stream) {
    const float* log_qi = (const float*)d_in[0];
    const float* G      = (const float*)d_in[1];
    const float* rho    = (const float*)d_in[2];
    // d_in[3] = n_var — unused by the reference
    const float* alpha  = (const float*)d_in[4];
    float* out = (float*)d_out;

    const int N = in_sizes[2];                 // 32768 batch items
    const int blocks = (N + 15) / 16;          // 16 items per block (4 per wave)
    mfnet_layer_kernel<<<blocks, 256, 0, stream>>>(log_qi, G, rho, alpha, out, N);
}